// Round 1
// baseline (67.169 us; speedup 1.0000x reference)
//
#include <hip/hip_runtime.h>
#include <math.h>

// Problem constants (from reference): N=8, L=8192, C=3
#define LEN 8192
#define NBATCH 8
#define NCH 3
#define BLK 256
#define BPN (LEN / BLK)            // 32 blocks per batch element
#define NBLOCKS (NBATCH * BPN)     // 256 blocks total
#define NQ 11                      // number of reduced quantities

// Quantity layout per block in d_ws (part[block][q]):
//  q=0..2 : BCE sum for channel 0,1,2 (global over n,l)
//  q=3    : sum  of input ch1  (per n)
//  q=4    : sum  of input ch2  (per n)
//  q=5    : sum  of input ch1^2 (per n)
//  q=6    : sum  of input ch2^2 (per n)
//  q=7    : sparsity sum input  ch1 (per n)   Σ |d| - 0.5*max(d,0), d = x[l]-x[0]
//  q=8    : sparsity sum input  ch2 (per n)
//  q=9    : sparsity sum target ch1 (per n)
//  q=10   : sparsity sum target ch2 (per n)

__device__ __forceinline__ float log_sigmoid(float x) {
    // log(sigmoid(x)) = min(x,0) - log1p(exp(-|x|))  (numerically stable)
    return fminf(x, 0.0f) - log1pf(expf(-fabsf(x)));
}

__device__ __forceinline__ float sp_term(float d) {
    // |d| - SPARSITY_B * max(d, 0), SPARSITY_B = 0.5
    return fabsf(d) - 0.5f * fmaxf(d, 0.0f);
}

__global__ __launch_bounds__(BLK) void partial_kernel(
        const float* __restrict__ inp,
        const float* __restrict__ tgt,
        const float* __restrict__ pw,
        float* __restrict__ part) {
    const int b = blockIdx.x;
    const int n = b >> 5;                       // 32 blocks per n
    const int l = ((b & 31) << 8) + threadIdx.x;
    const float* ip = inp + (size_t)n * LEN * NCH;
    const float* tp = tgt + (size_t)n * LEN * NCH;

    // this thread's point (all 3 channels)
    const float x0 = ip[l * 3 + 0];
    const float x1 = ip[l * 3 + 1];
    const float x2 = ip[l * 3 + 2];
    const float t0 = tp[l * 3 + 0];
    const float t1 = tp[l * 3 + 1];
    const float t2 = tp[l * 3 + 2];

    // l=0 base values for the sparsity diffs (uniform per block -> cached/broadcast)
    const float bi1 = ip[1], bi2 = ip[2];
    const float bt1 = tp[1], bt2 = tp[2];

    const float pw0 = pw[0], pw1 = pw[1], pw2 = pw[2];

    // BCE-with-logits, per channel: -(pos_w * t * logsig(x) + (1-t) * logsig(-x))
    float v[NQ];
    {
        float ls0 = log_sigmoid(x0), ln0 = log_sigmoid(-x0);
        float ls1 = log_sigmoid(x1), ln1 = log_sigmoid(-x1);
        float ls2 = log_sigmoid(x2), ln2 = log_sigmoid(-x2);
        v[0] = -(pw0 * t0 * ls0 + (1.0f - t0) * ln0);
        v[1] = -(pw1 * t1 * ls1 + (1.0f - t1) * ln1);
        v[2] = -(pw2 * t2 * ls2 + (1.0f - t2) * ln2);
    }
    // proximity moments (channels 1,2 of input)
    v[3] = x1;
    v[4] = x2;
    v[5] = x1 * x1;
    v[6] = x2 * x2;
    // sparsity partial terms; l==0 contributes exactly 0 so no branch needed
    v[7]  = sp_term(x1 - bi1);
    v[8]  = sp_term(x2 - bi2);
    v[9]  = sp_term(t1 - bt1);
    v[10] = sp_term(t2 - bt2);

    // block reduction: 64-wide shuffle tree, then LDS across the 4 waves
    __shared__ float red[4][NQ];
    const int lane = threadIdx.x & 63;
    const int wv   = threadIdx.x >> 6;
#pragma unroll
    for (int q = 0; q < NQ; ++q) {
        float s = v[q];
#pragma unroll
        for (int off = 32; off >= 1; off >>= 1) s += __shfl_down(s, off, 64);
        if (lane == 0) red[wv][q] = s;
    }
    __syncthreads();
    if (threadIdx.x < NQ) {
        const int q = threadIdx.x;
        part[b * NQ + q] = red[0][q] + red[1][q] + red[2][q] + red[3][q];
    }
}

__global__ __launch_bounds__(BLK) void finalize_kernel(
        const float* __restrict__ part,
        const float* __restrict__ cw,
        float* __restrict__ out) {
    const int t = threadIdx.x;   // 256 threads; thread t owns block t's partials
    float v[NQ];
#pragma unroll
    for (int q = 0; q < NQ; ++q) v[q] = part[t * NQ + q];

    const int lane = t & 63;
    const int wv   = t >> 6;
    __shared__ float bceS[4][3];
    __shared__ float perN[NBATCH][8];

    // q=0..2: global reduce over all 256 partial blocks
#pragma unroll
    for (int q = 0; q < 3; ++q) {
        float s = v[q];
#pragma unroll
        for (int off = 32; off >= 1; off >>= 1) s += __shfl_down(s, off, 64);
        if (lane == 0) bceS[wv][q] = s;
    }
    // q=3..10: segmented 32-wide reduce; segment g = t>>5 equals batch index n
#pragma unroll
    for (int q = 3; q < NQ; ++q) {
        float s = v[q];
#pragma unroll
        for (int off = 16; off >= 1; off >>= 1) s += __shfl_down(s, off, 32);
        if ((t & 31) == 0) perN[t >> 5][q - 3] = s;
    }
    __syncthreads();

    if (t == 0) {
        float loss = 0.0f;
        const float invNL = 1.0f / (float)(NBATCH * LEN);
#pragma unroll
        for (int c = 0; c < 3; ++c) {
            float s = bceS[0][c] + bceS[1][c] + bceS[2][c] + bceS[3][c];
            loss += 10.0f * cw[c] * (s * invNL);
        }
#pragma unroll
        for (int n = 0; n < NBATCH; ++n) {
            const float sum1 = perN[n][0], sum2 = perN[n][1];
            const float e1   = perN[n][2], e2   = perN[n][3];
            const float norm = sqrtf(e1 * e2);
            // mean(cc)/norm + penalty ; Σ(full cross-corr) = Σs1 * Σs2
            loss += (sum1 * sum2) / (norm * (float)(2 * LEN - 1))
                    + 1.0f - sqrtf(e1 + e2) / norm;
#pragma unroll
            for (int c = 0; c < 2; ++c) {
                const float si = 0.1f * perN[n][4 + c];  // SPARSITY_A = 0.1
                const float st = 0.1f * perN[n][6 + c];
                loss += fabsf(si - st) / (st + 1.0f);
            }
        }
        out[0] = loss;
    }
}

extern "C" void kernel_launch(void* const* d_in, const int* in_sizes, int n_in,
                              void* d_out, int out_size, void* d_ws, size_t ws_size,
                              hipStream_t stream) {
    const float* inp = (const float*)d_in[0];   // (N, L, C) f32
    const float* tgt = (const float*)d_in[1];   // (N, L, C) f32
    const float* cw  = (const float*)d_in[2];   // (C,) f32
    const float* pw  = (const float*)d_in[3];   // (C,) f32
    float* part = (float*)d_ws;                 // NBLOCKS * NQ floats

    partial_kernel<<<NBLOCKS, BLK, 0, stream>>>(inp, tgt, pw, part);
    finalize_kernel<<<1, BLK, 0, stream>>>(part, cw, (float*)d_out);
}